// Round 7
// baseline (414.356 us; speedup 1.0000x reference)
//
#include <hip/hip_runtime.h>

#define N_NODES 50000
#define N_EDGES 800000
#define D 128
#define BN_EPS 1e-5f

#define NBUCK 391        // ceil(N_NODES / 128)
#define BSHIFT 7         // 128 nodes per bucket
#define S1_BLOCKS 256
#define EPB 3125         // edges per histogram/scatter block (256*3125 == 800000)
#define CVT_BLOCKS 6250  // N_NODES*D/4 / 256
#define PACK_BLOCKS 384  // 3*32768 / 256

typedef __attribute__((ext_vector_type(8))) short bf16x8;
typedef __attribute__((ext_vector_type(4))) float f32x4;

// fp32 -> bf16 (RNE)
__device__ inline unsigned short f2bf(float f) {
    unsigned int u = __float_as_uint(f);
    u = (u + 0x7FFF + ((u >> 16) & 1)) >> 16;
    return (unsigned short)u;
}

__device__ inline float bf2f(unsigned short b) {
    return __uint_as_float(((unsigned)b) << 16);
}

// ---------------- fused prep: convert_x | edge histogram | pack_w (+zero) ----------

__global__ void fused_prep(const float* __restrict__ x, unsigned short* __restrict__ x16,
                           const int* __restrict__ dst, int* __restrict__ hist,
                           const float* __restrict__ Ws0, const float* __restrict__ Wn0,
                           const float* __restrict__ Ws1, const float* __restrict__ Wn1,
                           const float* __restrict__ Ws2, const float* __restrict__ Wn2,
                           unsigned short* __restrict__ Wf, float* __restrict__ statsg,
                           int* __restrict__ gcnt) {
    __shared__ int lh[NBUCK];
    const int bid = blockIdx.x, t = threadIdx.x;

    if (bid < CVT_BLOCKS) {
        int idx = bid * 256 + t;
        float4 v = ((const float4*)x)[idx];
        ushort4 o;
        o.x = f2bf(v.x); o.y = f2bf(v.y); o.z = f2bf(v.z); o.w = f2bf(v.w);
        ((ushort4*)x16)[idx] = o;
    } else if (bid < CVT_BLOCKS + S1_BLOCKS) {
        int blk = bid - CVT_BLOCKS;
        for (int i = t; i < NBUCK; i += 256) lh[i] = 0;
        __syncthreads();
        int e0 = blk * EPB;
        for (int i = 0; i < 13; i++) {
            int k = t + i * 256;
            if (k < EPB) atomicAdd(&lh[dst[e0 + k] >> BSHIFT], 1);
        }
        __syncthreads();
        for (int i = t; i < NBUCK; i += 256) hist[blk * NBUCK + i] = lh[i];
    } else {
        if (bid == CVT_BLOCKS + S1_BLOCKS) {   // zero BN stats (both layers) + barrier
            statsg[t] = 0.f; statsg[t + 256] = 0.f;
            if (t == 0) *gcnt = 0;
        }
        // pack weights into MFMA B-fragment order:
        // Wf[layer][kt(8)][nt(8)][lane(64)][j(8)], lane l holds
        // B[kt*32 + 8*(l>>4) + j][nt*16 + (l&15)].
        int idx = (bid - (CVT_BLOCKS + S1_BLOCKS)) * 256 + t;
        if (idx < 3 * 32768) {
            int layer = idx >> 15;
            int rem = idx & 32767;
            int kt = rem >> 12;
            int nt = (rem >> 9) & 7;
            int lane = (rem >> 3) & 63;
            int j = rem & 7;
            int k = kt * 32 + (lane >> 4) * 8 + j;
            int n = nt * 16 + (lane & 15);
            const float* Wsrc;
            if (layer == 0) Wsrc = (k < 128) ? Ws0 : Wn0;
            else if (layer == 1) Wsrc = (k < 128) ? Ws1 : Wn1;
            else Wsrc = (k < 128) ? Ws2 : Wn2;
            Wf[idx] = f2bf(Wsrc[(k & 127) * D + n]);
        }
    }
}

// ---------------- software grid barrier (256 co-resident blocks) ----------------
// 256 blocks x 256 threads on 256 CUs is capacity-guaranteed co-resident.
// Same construction as cooperative-groups grid.sync: release fence + device-scope
// atomic arrive + spin + acquire fence (handles cross-XCD L2 via fence semantics).

__device__ __forceinline__ void gbar(int* cnt, int target) {
    __syncthreads();
    if (threadIdx.x == 0) {
        __threadfence();
        atomicAdd(cnt, 1);
        while (atomicAdd(cnt, 0) < target) __builtin_amdgcn_s_sleep(2);
        __threadfence();
    }
    __syncthreads();
}

// ---------------- sort_all: s2a + s2b + s3 + s4 in one dispatch ----------------

__global__ __launch_bounds__(256) void sort_all(
    const int* __restrict__ src, const int* __restrict__ dst, int* __restrict__ hist,
    int* __restrict__ bucketTotal, int* __restrict__ bucketStart,
    unsigned int* __restrict__ rec, unsigned short* __restrict__ csr,
    int* __restrict__ degi, int* __restrict__ offsets, float* __restrict__ inv_deg,
    int* __restrict__ gcnt) {
    __shared__ int smem[512];
    const int t = threadIdx.x;
    const int blk = blockIdx.x;

    // Phase A: per-bucket exclusive prefix over the 256 histogram blocks
    for (int b = blk; b < NBUCK; b += 256) {
        int v = hist[t * NBUCK + b];
        smem[t] = v;
        __syncthreads();
        for (int off = 1; off < 256; off <<= 1) {
            int x = (t >= off) ? smem[t - off] : 0;
            __syncthreads();
            smem[t] += x;
            __syncthreads();
        }
        hist[t * NBUCK + b] = smem[t] - v;
        if (t == 255) bucketTotal[b] = smem[255];
        __syncthreads();
    }
    gbar(gcnt, 256);

    // Phase B: exclusive scan of bucket totals (block 0; 2 slots/thread)
    if (blk == 0) {
        int i1 = t + 256;
        int v0 = (t < NBUCK) ? bucketTotal[t] : 0;
        int v1 = (i1 < NBUCK) ? bucketTotal[i1] : 0;
        smem[t] = v0; smem[i1] = v1;
        __syncthreads();
        for (int off = 1; off < 512; off <<= 1) {
            int x0 = (t >= off) ? smem[t - off] : 0;
            int x1 = (i1 >= off) ? smem[i1 - off] : 0;
            __syncthreads();
            smem[t] += x0; smem[i1] += x1;
            __syncthreads();
        }
        if (t < NBUCK) bucketStart[t] = smem[t] - v0;
        if (i1 < NBUCK) bucketStart[i1] = smem[i1] - v1;
        if (t == 0) bucketStart[NBUCK] = N_EDGES;
    }
    gbar(gcnt, 512);

    // Phase C: scatter packed records (dst&127)<<16 | src, bucket-grouped.
    // Each (block,bucket) slot range is consecutive & block-exclusive -> L2 combine.
    for (int i = t; i < NBUCK; i += 256)
        smem[i] = bucketStart[i] + hist[blk * NBUCK + i];
    __syncthreads();
    {
        int e0 = blk * EPB;
        for (int i = 0; i < 13; i++) {
            int k = t + i * 256;
            if (k < EPB) {
                int e = e0 + k;
                int d = dst[e];
                int p = atomicAdd(&smem[d >> BSHIFT], 1);
                rec[p] = ((unsigned)(d & 127) << 16) | (unsigned)src[e];
            }
        }
    }
    gbar(gcnt, 768);

    // Phase D: per-bucket counting sort -> CSR(ushort) + degrees
    int* lh = smem;
    int* ls = smem + 128;
    int* lcur = smem + 256;
    for (int b = blk; b < NBUCK; b += 256) {
        int start = bucketStart[b], end = bucketStart[b + 1];
        __syncthreads();
        if (t < 128) lh[t] = 0;
        __syncthreads();
        for (int e = start + t; e < end; e += 256)
            atomicAdd(&lh[rec[e] >> 16], 1);
        __syncthreads();
        int v = 0;
        if (t < 128) { v = lh[t]; ls[t] = v; }
        __syncthreads();
        for (int off = 1; off < 128; off <<= 1) {
            int x = 0;
            if (t < 128 && t >= off) x = ls[t - off];
            __syncthreads();
            if (t < 128) ls[t] += x;
            __syncthreads();
        }
        int node0 = b << BSHIFT;
        if (t < 128) {
            int excl = ls[t] - v;
            lcur[t] = start + excl;
            int node = node0 + t;
            if (node < N_NODES) {
                degi[node] = v;
                offsets[node] = start + excl;
                inv_deg[node] = 1.0f / (float)max(v, 1);
            }
        }
        __syncthreads();
        for (int e = start + t; e < end; e += 256) {
            unsigned r = rec[e];
            int p = atomicAdd(&lcur[r >> 16], 1);
            csr[p] = (unsigned short)(r & 0xFFFFu);
        }
    }
}

// ---------------- mean aggregation with on-the-fly BN+ReLU ----------------
// h16 holds PRE-BN activations; consumers apply bn+relu (statsIn != nullptr).
// Separate kernel on purpose: gather is latency-bound, needs max occupancy
// (round-5 fusion into the GEMM block regressed 375->394 us).

__global__ void aggregate16(const unsigned short* __restrict__ h16,
                            const unsigned short* __restrict__ csr, const int* __restrict__ offsets,
                            const int* __restrict__ degi, const float* __restrict__ inv_deg,
                            unsigned short* __restrict__ mean16,
                            const float* __restrict__ statsIn,
                            const float* __restrict__ gammaIn, const float* __restrict__ betaIn) {
    int node = blockIdx.x * 16 + (threadIdx.x >> 4);
    if (node >= N_NODES) return;
    int c = threadIdx.x & 15;
    int beg = offsets[node], n = degi[node];
    float a[8];
#pragma unroll
    for (int j = 0; j < 8; j++) a[j] = 0.f;

    if (statsIn) {
        const float invN = 1.0f / (float)N_NODES;
        float sc[8], sh[8];
#pragma unroll
        for (int j = 0; j < 8; j++) {
            int col = c * 8 + j;
            float m = statsIn[col] * invN;
            float var = statsIn[128 + col] * invN - m * m;
            float s = rsqrtf(var + BN_EPS) * gammaIn[col];
            sc[j] = s;
            sh[j] = betaIn[col] - m * s;
        }
        for (int i = 0; i < n; i++) {
            int s = csr[beg + i];
            uint4 v = *(const uint4*)(h16 + (size_t)s * D + c * 8);
            unsigned w[4] = {v.x, v.y, v.z, v.w};
#pragma unroll
            for (int p = 0; p < 4; p++) {
                float lo = __uint_as_float(w[p] << 16);
                float hi = __uint_as_float(w[p] & 0xffff0000u);
                a[2 * p]     += fmaxf(lo * sc[2 * p]     + sh[2 * p],     0.f);
                a[2 * p + 1] += fmaxf(hi * sc[2 * p + 1] + sh[2 * p + 1], 0.f);
            }
        }
    } else {
        for (int i = 0; i < n; i++) {
            int s = csr[beg + i];
            uint4 v = *(const uint4*)(h16 + (size_t)s * D + c * 8);
            unsigned w[4] = {v.x, v.y, v.z, v.w};
#pragma unroll
            for (int p = 0; p < 4; p++) {
                a[2 * p]     += __uint_as_float(w[p] << 16);
                a[2 * p + 1] += __uint_as_float(w[p] & 0xffff0000u);
            }
        }
    }

    float w = inv_deg[node];
    uint4 o;
    o.x = ((unsigned)f2bf(a[1] * w) << 16) | f2bf(a[0] * w);
    o.y = ((unsigned)f2bf(a[3] * w) << 16) | f2bf(a[2] * w);
    o.z = ((unsigned)f2bf(a[5] * w) << 16) | f2bf(a[4] * w);
    o.w = ((unsigned)f2bf(a[7] * w) << 16) | f2bf(a[6] * w);
    *(uint4*)(mean16 + (size_t)node * D + c * 8) = o;
}

// ---------------- MFMA SAGE GEMM + fused BN col-stats ----------------
// out_raw = [bn_relu(h_raw) | mean] @ Wf + b (self half transformed on the fly
// when statsIn != nullptr; mean16 is already post-BN from aggregate16).
// Epilogue: bf16 raw store (layers 0/1) or fp32 (layer 2) + column sum/sumsq.
// C/D layout (m89-verified): col = lane&15, row = (lane>>4)*4 + reg.

__global__ __launch_bounds__(256) void sage_gemm(
    const unsigned short* __restrict__ h16, const unsigned short* __restrict__ mean16,
    const unsigned short* __restrict__ Wf, const float* __restrict__ bias,
    unsigned short* __restrict__ out16, float* __restrict__ outf,
    float* __restrict__ statsOut,
    const float* __restrict__ statsIn,
    const float* __restrict__ gammaIn, const float* __restrict__ betaIn) {
    __shared__ float sstat[256];
    const int t = threadIdx.x;
    const int lane = t & 63;
    const int wave = t >> 6;
    const int m = lane & 15;
    const int quad = lane >> 4;
    const int wrow0 = blockIdx.x * 64 + wave * 16;
    const float invN = 1.0f / (float)N_NODES;

    if (statsOut) {
        sstat[t] = 0.f;
        __syncthreads();
    }

    int arow = wrow0 + m;
    if (arow >= N_NODES) arow = N_NODES - 1;

    f32x4 acc[8];
#pragma unroll
    for (int i = 0; i < 8; i++) acc[i] = (f32x4)(0.f);

#pragma unroll
    for (int kt = 0; kt < 8; kt++) {
        bf16x8 af;
        if (kt < 4) {
            af = *(const bf16x8*)(h16 + (size_t)arow * D + kt * 32 + quad * 8);
            if (statsIn) {   // wave-uniform branch: apply bn+relu to self fragment
                int c0 = kt * 32 + quad * 8;
#pragma unroll
                for (int j = 0; j < 8; j++) {
                    int col = c0 + j;
                    float mm = statsIn[col] * invN;
                    float var = statsIn[128 + col] * invN - mm * mm;
                    float s = rsqrtf(var + BN_EPS) * gammaIn[col];
                    float raw = bf2f((unsigned short)af[j]);
                    float v = fmaxf(raw * s + (betaIn[col] - mm * s), 0.f);
                    af[j] = (short)f2bf(v);
                }
            }
        } else {
            af = *(const bf16x8*)(mean16 + (size_t)arow * D + (kt - 4) * 32 + quad * 8);
        }
#pragma unroll
        for (int nt = 0; nt < 8; nt++) {
            bf16x8 bf = *(const bf16x8*)(Wf + ((kt * 8 + nt) * 64 + lane) * 8);
            acc[nt] = __builtin_amdgcn_mfma_f32_16x16x32_bf16(af, bf, acc[nt], 0, 0, 0);
        }
    }

    const bool do16 = (out16 != nullptr);
#pragma unroll
    for (int nt = 0; nt < 8; nt++) {
        int cidx = nt * 16 + m;
        float bv = bias[cidx];
        float s = 0.f, q = 0.f;
#pragma unroll
        for (int reg = 0; reg < 4; reg++) {
            int r = wrow0 + quad * 4 + reg;
            float v = acc[nt][reg] + bv;
            if (r < N_NODES) {
                if (do16) out16[(size_t)r * D + cidx] = f2bf(v);
                else      outf[(size_t)r * D + cidx] = v;
                s += v; q += v * v;
            }
        }
        if (statsOut) {
            s += __shfl_xor(s, 16); s += __shfl_xor(s, 32);
            q += __shfl_xor(q, 16); q += __shfl_xor(q, 32);
            if (quad == 0) {
                atomicAdd(&sstat[cidx], s);
                atomicAdd(&sstat[128 + cidx], q);
            }
        }
    }
    if (statsOut) {
        __syncthreads();
        atomicAdd(&statsOut[t], sstat[t]);
    }
}

// ---------------- launch ----------------

extern "C" void kernel_launch(void* const* d_in, const int* in_sizes, int n_in,
                              void* d_out, int out_size, void* d_ws, size_t ws_size,
                              hipStream_t stream) {
    const float* x   = (const float*)d_in[0];
    const int* src   = (const int*)d_in[1];
    const int* dst   = (const int*)d_in[2];
    const float* Ws0 = (const float*)d_in[3];
    const float* Wn0 = (const float*)d_in[4];
    const float* b0  = (const float*)d_in[5];
    const float* Ws1 = (const float*)d_in[6];
    const float* Wn1 = (const float*)d_in[7];
    const float* b1  = (const float*)d_in[8];
    const float* Ws2 = (const float*)d_in[9];
    const float* Wn2 = (const float*)d_in[10];
    const float* b2  = (const float*)d_in[11];
    const float* g0  = (const float*)d_in[12];
    const float* be0 = (const float*)d_in[13];
    const float* g1  = (const float*)d_in[14];
    const float* be1 = (const float*)d_in[15];

    char* base = (char*)d_ws;
    size_t NND = (size_t)N_NODES * D;
    unsigned short* X16    = (unsigned short*)base;                 // 12.8 MB: L0 in, then L1 raw out
    unsigned short* H16    = (unsigned short*)(base + NND * 2);     // 12.8 MB: L0 raw out
    unsigned short* mean16 = (unsigned short*)(base + 2 * NND * 2); // 12.8 MB
    char* p = base + 6 * NND;
    unsigned short* Wf = (unsigned short*)p;  p += 3 * 32768 * 2;                  // 192 KB
    int* hist          = (int*)p;             p += (size_t)S1_BLOCKS * NBUCK * 4;  // 400 KB
    int* bucketTotal   = (int*)p;             p += 1568;
    int* bucketStart   = (int*)p;             p += 1568;
    unsigned int* rec  = (unsigned int*)p;    p += (size_t)N_EDGES * 4;            // 3.2 MB
    unsigned short* csr = (unsigned short*)p; p += (size_t)N_EDGES * 2;            // 1.6 MB
    int* degi    = (int*)p;                   p += N_NODES * 4;
    int* offsets = (int*)p;                   p += N_NODES * 4;
    float* inv_deg = (float*)p;               p += N_NODES * 4;
    float* stats   = (float*)p;               p += 2048;  // [2][sum128|sumsq128]
    int* gcnt      = (int*)p;                 p += 64;
    float* stats0 = stats, *stats1 = stats + 256;

    // prep: feature convert + edge histogram + weight pack + zero stats/barrier
    fused_prep<<<CVT_BLOCKS + S1_BLOCKS + PACK_BLOCKS, 256, 0, stream>>>(
        x, X16, dst, hist, Ws0, Wn0, Ws1, Wn1, Ws2, Wn2, Wf, stats, gcnt);
    // CSR build: one dispatch, internal grid barriers (256 co-resident blocks)
    sort_all<<<256, 256, 0, stream>>>(src, dst, hist, bucketTotal, bucketStart,
                                      rec, csr, degi, offsets, inv_deg, gcnt);

    const int AGG_B = (N_NODES + 15) / 16;   // 3125
    const int GEMM_B = (N_NODES + 63) / 64;  // 782

    // Layer 0: X16 (no BN) -> H16 raw + stats0
    aggregate16<<<AGG_B, 256, 0, stream>>>(X16, csr, offsets, degi, inv_deg, mean16,
                                           nullptr, nullptr, nullptr);
    sage_gemm<<<GEMM_B, 256, 0, stream>>>(X16, mean16, Wf, b0, H16, nullptr,
                                          stats0, nullptr, nullptr, nullptr);

    // Layer 1: consumers apply bn0+relu to H16 raw; -> X16 raw + stats1
    aggregate16<<<AGG_B, 256, 0, stream>>>(H16, csr, offsets, degi, inv_deg, mean16,
                                           stats0, g0, be0);
    sage_gemm<<<GEMM_B, 256, 0, stream>>>(H16, mean16, Wf + 32768, b1, X16, nullptr,
                                          stats1, stats0, g0, be0);

    // Layer 2: consumers apply bn1+relu to X16 raw; -> d_out fp32
    aggregate16<<<AGG_B, 256, 0, stream>>>(X16, csr, offsets, degi, inv_deg, mean16,
                                           stats1, g1, be1);
    sage_gemm<<<GEMM_B, 256, 0, stream>>>(X16, mean16, Wf + 65536, b2, nullptr,
                                          (float*)d_out, nullptr, stats1, g1, be1);
}

// Round 8
// 349.262 us; speedup vs baseline: 1.1864x; 1.1864x over previous
//
#include <hip/hip_runtime.h>

#define N_NODES 50000
#define N_EDGES 800000
#define D 128
#define BN_EPS 1e-5f

#define NBUCK 391        // ceil(N_NODES / 128)
#define BSHIFT 7         // 128 nodes per bucket
#define S1_BLOCKS 256
#define EPB 3125         // edges per histogram/scatter block (256*3125 == 800000)
#define CVT_BLOCKS 6250  // N_NODES*D/4 / 256
#define PACK_BLOCKS 384  // 3*32768 / 256

typedef __attribute__((ext_vector_type(8))) short bf16x8;
typedef __attribute__((ext_vector_type(4))) float f32x4;

// fp32 -> bf16 (RNE)
__device__ inline unsigned short f2bf(float f) {
    unsigned int u = __float_as_uint(f);
    u = (u + 0x7FFF + ((u >> 16) & 1)) >> 16;
    return (unsigned short)u;
}

__device__ inline float bf2f(unsigned short b) {
    return __uint_as_float(((unsigned)b) << 16);
}

// ---------------- fused prep: convert_x | edge histogram | pack_w (+zero) ----------

__global__ void fused_prep(const float* __restrict__ x, unsigned short* __restrict__ x16,
                           const int* __restrict__ dst, int* __restrict__ hist,
                           const float* __restrict__ Ws0, const float* __restrict__ Wn0,
                           const float* __restrict__ Ws1, const float* __restrict__ Wn1,
                           const float* __restrict__ Ws2, const float* __restrict__ Wn2,
                           unsigned short* __restrict__ Wf, float* __restrict__ statsg) {
    __shared__ int lh[NBUCK];
    const int bid = blockIdx.x, t = threadIdx.x;

    if (bid < CVT_BLOCKS) {
        int idx = bid * 256 + t;
        float4 v = ((const float4*)x)[idx];
        ushort4 o;
        o.x = f2bf(v.x); o.y = f2bf(v.y); o.z = f2bf(v.z); o.w = f2bf(v.w);
        ((ushort4*)x16)[idx] = o;
    } else if (bid < CVT_BLOCKS + S1_BLOCKS) {
        int blk = bid - CVT_BLOCKS;
        for (int i = t; i < NBUCK; i += 256) lh[i] = 0;
        __syncthreads();
        int e0 = blk * EPB;
        for (int i = 0; i < 13; i++) {
            int k = t + i * 256;
            if (k < EPB) atomicAdd(&lh[dst[e0 + k] >> BSHIFT], 1);
        }
        __syncthreads();
        for (int i = t; i < NBUCK; i += 256) hist[blk * NBUCK + i] = lh[i];
    } else {
        if (bid == CVT_BLOCKS + S1_BLOCKS) {   // zero BN stats (both layers)
            statsg[t] = 0.f; statsg[t + 256] = 0.f;
        }
        // pack weights into MFMA B-fragment order:
        // Wf[layer][kt(8)][nt(8)][lane(64)][j(8)], lane l holds
        // B[kt*32 + 8*(l>>4) + j][nt*16 + (l&15)].
        int idx = (bid - (CVT_BLOCKS + S1_BLOCKS)) * 256 + t;
        if (idx < 3 * 32768) {
            int layer = idx >> 15;
            int rem = idx & 32767;
            int kt = rem >> 12;
            int nt = (rem >> 9) & 7;
            int lane = (rem >> 3) & 63;
            int j = rem & 7;
            int k = kt * 32 + (lane >> 4) * 8 + j;
            int n = nt * 16 + (lane & 15);
            const float* Wsrc;
            if (layer == 0) Wsrc = (k < 128) ? Ws0 : Wn0;
            else if (layer == 1) Wsrc = (k < 128) ? Ws1 : Wn1;
            else Wsrc = (k < 128) ? Ws2 : Wn2;
            Wf[idx] = f2bf(Wsrc[(k & 127) * D + n]);
        }
    }
}

// ---------------- S2a: per-bucket exclusive prefix over blocks ----------------
// Separate kernels on purpose: round-7's grid-barrier merge (sort_all) ran 97 us
// vs ~35 us for this 4-kernel pipeline — barrier serialization at 1 block/CU.

__global__ void s2a(int* __restrict__ hist, int* __restrict__ bucketTotal) {
    __shared__ int s[S1_BLOCKS];
    int b = blockIdx.x, t = threadIdx.x;
    int v = hist[t * NBUCK + b];
    s[t] = v;
    __syncthreads();
    for (int off = 1; off < S1_BLOCKS; off <<= 1) {
        int x = (t >= off) ? s[t - off] : 0;
        __syncthreads();
        s[t] += x;
        __syncthreads();
    }
    hist[t * NBUCK + b] = s[t] - v;
    if (t == S1_BLOCKS - 1) bucketTotal[b] = s[t];
}

// ---------------- S2b: exclusive scan of bucket totals ----------------

__global__ void s2b(const int* __restrict__ bucketTotal, int* __restrict__ bucketStart) {
    __shared__ int s[512];
    int t = threadIdx.x;
    int v = (t < NBUCK) ? bucketTotal[t] : 0;
    s[t] = v;
    __syncthreads();
    for (int off = 1; off < 512; off <<= 1) {
        int x = (t >= off) ? s[t - off] : 0;
        __syncthreads();
        s[t] += x;
        __syncthreads();
    }
    if (t <= NBUCK) bucketStart[t] = s[t] - v;
}

// ---------------- S3: scatter packed records, bucket-grouped ----------------

__global__ void s3_scatter(const int* __restrict__ src, const int* __restrict__ dst,
                           const int* __restrict__ hist, const int* __restrict__ bucketStart,
                           unsigned int* __restrict__ rec) {
    __shared__ int base[NBUCK];
    int blk = blockIdx.x, t = threadIdx.x;
    for (int i = t; i < NBUCK; i += 256)
        base[i] = bucketStart[i] + hist[blk * NBUCK + i];
    __syncthreads();
    int e0 = blk * EPB;
    for (int i = 0; i < 13; i++) {
        int k = t + i * 256;
        if (k < EPB) {
            int e = e0 + k;
            int d = dst[e];
            int p = atomicAdd(&base[d >> BSHIFT], 1);
            rec[p] = ((unsigned)(d & 127) << 16) | (unsigned)src[e];
        }
    }
}

// ---------------- S4: per-bucket counting sort -> CSR + degrees ----------------

__global__ void s4_build(const unsigned int* __restrict__ rec, const int* __restrict__ bucketStart,
                         unsigned short* __restrict__ csr, int* __restrict__ degi,
                         int* __restrict__ offsets, float* __restrict__ inv_deg) {
    __shared__ int lh[128];
    __shared__ int ls[128];
    __shared__ int lcur[128];
    int b = blockIdx.x, t = threadIdx.x;
    int start = bucketStart[b], end = bucketStart[b + 1];

    if (t < 128) lh[t] = 0;
    __syncthreads();
    for (int e = start + t; e < end; e += 256)
        atomicAdd(&lh[rec[e] >> 16], 1);
    __syncthreads();

    int v = 0;
    if (t < 128) { v = lh[t]; ls[t] = v; }
    __syncthreads();
    for (int off = 1; off < 128; off <<= 1) {
        int x = 0;
        if (t < 128 && t >= off) x = ls[t - off];
        __syncthreads();
        if (t < 128) ls[t] += x;
        __syncthreads();
    }

    int node0 = b << BSHIFT;
    if (t < 128) {
        int excl = ls[t] - v;
        lcur[t] = start + excl;
        int node = node0 + t;
        if (node < N_NODES) {
            degi[node] = v;
            offsets[node] = start + excl;
            inv_deg[node] = 1.0f / (float)max(v, 1);
        }
    }
    __syncthreads();
    for (int e = start + t; e < end; e += 256) {
        unsigned r = rec[e];
        int p = atomicAdd(&lcur[r >> 16], 1);
        csr[p] = (unsigned short)(r & 0xFFFFu);
    }
}

// ---------------- mean aggregation with on-the-fly BN+ReLU ----------------
// h16 holds PRE-BN activations; consumers apply bn+relu (statsIn != nullptr).
// Separate kernel on purpose: gather is latency-bound, needs max occupancy
// (round-5 fusion into the GEMM block regressed 375->394 us).

__global__ void aggregate16(const unsigned short* __restrict__ h16,
                            const unsigned short* __restrict__ csr, const int* __restrict__ offsets,
                            const int* __restrict__ degi, const float* __restrict__ inv_deg,
                            unsigned short* __restrict__ mean16,
                            const float* __restrict__ statsIn,
                            const float* __restrict__ gammaIn, const float* __restrict__ betaIn) {
    int node = blockIdx.x * 16 + (threadIdx.x >> 4);
    if (node >= N_NODES) return;
    int c = threadIdx.x & 15;
    int beg = offsets[node], n = degi[node];
    float a[8];
#pragma unroll
    for (int j = 0; j < 8; j++) a[j] = 0.f;

    if (statsIn) {
        const float invN = 1.0f / (float)N_NODES;
        float sc[8], sh[8];
#pragma unroll
        for (int j = 0; j < 8; j++) {
            int col = c * 8 + j;
            float m = statsIn[col] * invN;
            float var = statsIn[128 + col] * invN - m * m;
            float s = rsqrtf(var + BN_EPS) * gammaIn[col];
            sc[j] = s;
            sh[j] = betaIn[col] - m * s;
        }
        for (int i = 0; i < n; i++) {
            int s = csr[beg + i];
            uint4 v = *(const uint4*)(h16 + (size_t)s * D + c * 8);
            unsigned w[4] = {v.x, v.y, v.z, v.w};
#pragma unroll
            for (int p = 0; p < 4; p++) {
                float lo = __uint_as_float(w[p] << 16);
                float hi = __uint_as_float(w[p] & 0xffff0000u);
                a[2 * p]     += fmaxf(lo * sc[2 * p]     + sh[2 * p],     0.f);
                a[2 * p + 1] += fmaxf(hi * sc[2 * p + 1] + sh[2 * p + 1], 0.f);
            }
        }
    } else {
        for (int i = 0; i < n; i++) {
            int s = csr[beg + i];
            uint4 v = *(const uint4*)(h16 + (size_t)s * D + c * 8);
            unsigned w[4] = {v.x, v.y, v.z, v.w};
#pragma unroll
            for (int p = 0; p < 4; p++) {
                a[2 * p]     += __uint_as_float(w[p] << 16);
                a[2 * p + 1] += __uint_as_float(w[p] & 0xffff0000u);
            }
        }
    }

    float w = inv_deg[node];
    uint4 o;
    o.x = ((unsigned)f2bf(a[1] * w) << 16) | f2bf(a[0] * w);
    o.y = ((unsigned)f2bf(a[3] * w) << 16) | f2bf(a[2] * w);
    o.z = ((unsigned)f2bf(a[5] * w) << 16) | f2bf(a[4] * w);
    o.w = ((unsigned)f2bf(a[7] * w) << 16) | f2bf(a[6] * w);
    *(uint4*)(mean16 + (size_t)node * D + c * 8) = o;
}

// ---------------- MFMA SAGE GEMM + fused BN col-stats ----------------
// out_raw = [bn_relu(h_raw) | mean] @ Wf + b (self half transformed on the fly
// when statsIn != nullptr; mean16 is already post-BN from aggregate16).
// Epilogue: bf16 raw store (layers 0/1) or fp32 (layer 2) + column sum/sumsq.
// C/D layout (m89-verified): col = lane&15, row = (lane>>4)*4 + reg.

__global__ __launch_bounds__(256) void sage_gemm(
    const unsigned short* __restrict__ h16, const unsigned short* __restrict__ mean16,
    const unsigned short* __restrict__ Wf, const float* __restrict__ bias,
    unsigned short* __restrict__ out16, float* __restrict__ outf,
    float* __restrict__ statsOut,
    const float* __restrict__ statsIn,
    const float* __restrict__ gammaIn, const float* __restrict__ betaIn) {
    __shared__ float sstat[256];
    const int t = threadIdx.x;
    const int lane = t & 63;
    const int wave = t >> 6;
    const int m = lane & 15;
    const int quad = lane >> 4;
    const int wrow0 = blockIdx.x * 64 + wave * 16;
    const float invN = 1.0f / (float)N_NODES;

    if (statsOut) {
        sstat[t] = 0.f;
        __syncthreads();
    }

    int arow = wrow0 + m;
    if (arow >= N_NODES) arow = N_NODES - 1;

    f32x4 acc[8];
#pragma unroll
    for (int i = 0; i < 8; i++) acc[i] = (f32x4)(0.f);

#pragma unroll
    for (int kt = 0; kt < 8; kt++) {
        bf16x8 af;
        if (kt < 4) {
            af = *(const bf16x8*)(h16 + (size_t)arow * D + kt * 32 + quad * 8);
            if (statsIn) {   // wave-uniform branch: apply bn+relu to self fragment
                int c0 = kt * 32 + quad * 8;
#pragma unroll
                for (int j = 0; j < 8; j++) {
                    int col = c0 + j;
                    float mm = statsIn[col] * invN;
                    float var = statsIn[128 + col] * invN - mm * mm;
                    float s = rsqrtf(var + BN_EPS) * gammaIn[col];
                    float raw = bf2f((unsigned short)af[j]);
                    float v = fmaxf(raw * s + (betaIn[col] - mm * s), 0.f);
                    af[j] = (short)f2bf(v);
                }
            }
        } else {
            af = *(const bf16x8*)(mean16 + (size_t)arow * D + (kt - 4) * 32 + quad * 8);
        }
#pragma unroll
        for (int nt = 0; nt < 8; nt++) {
            bf16x8 bf = *(const bf16x8*)(Wf + ((kt * 8 + nt) * 64 + lane) * 8);
            acc[nt] = __builtin_amdgcn_mfma_f32_16x16x32_bf16(af, bf, acc[nt], 0, 0, 0);
        }
    }

    const bool do16 = (out16 != nullptr);
#pragma unroll
    for (int nt = 0; nt < 8; nt++) {
        int cidx = nt * 16 + m;
        float bv = bias[cidx];
        float s = 0.f, q = 0.f;
#pragma unroll
        for (int reg = 0; reg < 4; reg++) {
            int r = wrow0 + quad * 4 + reg;
            float v = acc[nt][reg] + bv;
            if (r < N_NODES) {
                if (do16) out16[(size_t)r * D + cidx] = f2bf(v);
                else      outf[(size_t)r * D + cidx] = v;
                s += v; q += v * v;
            }
        }
        if (statsOut) {
            s += __shfl_xor(s, 16); s += __shfl_xor(s, 32);
            q += __shfl_xor(q, 16); q += __shfl_xor(q, 32);
            if (quad == 0) {
                atomicAdd(&sstat[cidx], s);
                atomicAdd(&sstat[128 + cidx], q);
            }
        }
    }
    if (statsOut) {
        __syncthreads();
        atomicAdd(&statsOut[t], sstat[t]);
    }
}

// ---------------- launch ----------------

extern "C" void kernel_launch(void* const* d_in, const int* in_sizes, int n_in,
                              void* d_out, int out_size, void* d_ws, size_t ws_size,
                              hipStream_t stream) {
    const float* x   = (const float*)d_in[0];
    const int* src   = (const int*)d_in[1];
    const int* dst   = (const int*)d_in[2];
    const float* Ws0 = (const float*)d_in[3];
    const float* Wn0 = (const float*)d_in[4];
    const float* b0  = (const float*)d_in[5];
    const float* Ws1 = (const float*)d_in[6];
    const float* Wn1 = (const float*)d_in[7];
    const float* b1  = (const float*)d_in[8];
    const float* Ws2 = (const float*)d_in[9];
    const float* Wn2 = (const float*)d_in[10];
    const float* b2  = (const float*)d_in[11];
    const float* g0  = (const float*)d_in[12];
    const float* be0 = (const float*)d_in[13];
    const float* g1  = (const float*)d_in[14];
    const float* be1 = (const float*)d_in[15];

    char* base = (char*)d_ws;
    size_t NND = (size_t)N_NODES * D;
    unsigned short* X16    = (unsigned short*)base;                 // 12.8 MB: L0 in, then L1 raw out
    unsigned short* H16    = (unsigned short*)(base + NND * 2);     // 12.8 MB: L0 raw out
    unsigned short* mean16 = (unsigned short*)(base + 2 * NND * 2); // 12.8 MB
    char* p = base + 6 * NND;
    unsigned short* Wf = (unsigned short*)p;  p += 3 * 32768 * 2;                  // 192 KB
    int* hist          = (int*)p;             p += (size_t)S1_BLOCKS * NBUCK * 4;  // 400 KB
    int* bucketTotal   = (int*)p;             p += 1568;
    int* bucketStart   = (int*)p;             p += 1568;
    unsigned int* rec  = (unsigned int*)p;    p += (size_t)N_EDGES * 4;            // 3.2 MB
    unsigned short* csr = (unsigned short*)p; p += (size_t)N_EDGES * 2;            // 1.6 MB
    int* degi    = (int*)p;                   p += N_NODES * 4;
    int* offsets = (int*)p;                   p += N_NODES * 4;
    float* inv_deg = (float*)p;               p += N_NODES * 4;
    float* stats   = (float*)p;               p += 2048;  // [2][sum128|sumsq128]
    float* stats0 = stats, *stats1 = stats + 256;

    // prep: feature convert + edge histogram + weight pack + zero stats
    fused_prep<<<CVT_BLOCKS + S1_BLOCKS + PACK_BLOCKS, 256, 0, stream>>>(
        x, X16, dst, hist, Ws0, Wn0, Ws1, Wn1, Ws2, Wn2, Wf, stats);
    // CSR build: 4 kernels, each at natural parallelism
    s2a<<<NBUCK, 256, 0, stream>>>(hist, bucketTotal);
    s2b<<<1, 512, 0, stream>>>(bucketTotal, bucketStart);
    s3_scatter<<<S1_BLOCKS, 256, 0, stream>>>(src, dst, hist, bucketStart, rec);
    s4_build<<<NBUCK, 256, 0, stream>>>(rec, bucketStart, csr, degi, offsets, inv_deg);

    const int AGG_B = (N_NODES + 15) / 16;   // 3125
    const int GEMM_B = (N_NODES + 63) / 64;  // 782

    // Layer 0: X16 (no BN) -> H16 raw + stats0
    aggregate16<<<AGG_B, 256, 0, stream>>>(X16, csr, offsets, degi, inv_deg, mean16,
                                           nullptr, nullptr, nullptr);
    sage_gemm<<<GEMM_B, 256, 0, stream>>>(X16, mean16, Wf, b0, H16, nullptr,
                                          stats0, nullptr, nullptr, nullptr);

    // Layer 1: consumers apply bn0+relu to H16 raw; -> X16 raw + stats1
    aggregate16<<<AGG_B, 256, 0, stream>>>(H16, csr, offsets, degi, inv_deg, mean16,
                                           stats0, g0, be0);
    sage_gemm<<<GEMM_B, 256, 0, stream>>>(H16, mean16, Wf + 32768, b1, X16, nullptr,
                                          stats1, stats0, g0, be0);

    // Layer 2: consumers apply bn1+relu to X16 raw; -> d_out fp32
    aggregate16<<<AGG_B, 256, 0, stream>>>(X16, csr, offsets, degi, inv_deg, mean16,
                                           stats1, g1, be1);
    sage_gemm<<<GEMM_B, 256, 0, stream>>>(X16, mean16, Wf + 65536, b2, nullptr,
                                          (float*)d_out, nullptr, stats1, g1, be1);
}

// Round 9
// 331.268 us; speedup vs baseline: 1.2508x; 1.0543x over previous
//
#include <hip/hip_runtime.h>

#define N_NODES 50000
#define N_EDGES 800000
#define D 128
#define BN_EPS 1e-5f

#define NBUCK 391        // ceil(N_NODES / 128)
#define BSHIFT 7         // 128 nodes per bucket
#define S1_BLOCKS 256
#define EPB 3125         // edges per histogram/scatter block (256*3125 == 800000)
#define CVT_BLOCKS 6250  // N_NODES*D/4 / 256
#define PACK_BLOCKS 384  // 3*32768 / 256

typedef __attribute__((ext_vector_type(8))) short bf16x8;
typedef __attribute__((ext_vector_type(4))) float f32x4;

// fp32 -> bf16 (RNE)
__device__ inline unsigned short f2bf(float f) {
    unsigned int u = __float_as_uint(f);
    u = (u + 0x7FFF + ((u >> 16) & 1)) >> 16;
    return (unsigned short)u;
}

__device__ inline float bf2f(unsigned short b) {
    return __uint_as_float(((unsigned)b) << 16);
}

__device__ __forceinline__ void acc_plain(float* a, uint4 v) {
    unsigned w[4] = {v.x, v.y, v.z, v.w};
#pragma unroll
    for (int p = 0; p < 4; p++) {
        a[2 * p]     += __uint_as_float(w[p] << 16);
        a[2 * p + 1] += __uint_as_float(w[p] & 0xffff0000u);
    }
}

__device__ __forceinline__ void acc_bn(float* a, uint4 v, const float* sc, const float* sh) {
    unsigned w[4] = {v.x, v.y, v.z, v.w};
#pragma unroll
    for (int p = 0; p < 4; p++) {
        float lo = __uint_as_float(w[p] << 16);
        float hi = __uint_as_float(w[p] & 0xffff0000u);
        a[2 * p]     += fmaxf(lo * sc[2 * p]     + sh[2 * p],     0.f);
        a[2 * p + 1] += fmaxf(hi * sc[2 * p + 1] + sh[2 * p + 1], 0.f);
    }
}

// ---------------- fused prep: convert_x | edge histogram | pack_w (+zero) ----------

__global__ void fused_prep(const float* __restrict__ x, unsigned short* __restrict__ x16,
                           const int* __restrict__ dst, int* __restrict__ hist,
                           const float* __restrict__ Ws0, const float* __restrict__ Wn0,
                           const float* __restrict__ Ws1, const float* __restrict__ Wn1,
                           const float* __restrict__ Ws2, const float* __restrict__ Wn2,
                           unsigned short* __restrict__ Wf, float* __restrict__ statsg) {
    __shared__ int lh[NBUCK];
    const int bid = blockIdx.x, t = threadIdx.x;

    if (bid < CVT_BLOCKS) {
        int idx = bid * 256 + t;
        float4 v = ((const float4*)x)[idx];
        ushort4 o;
        o.x = f2bf(v.x); o.y = f2bf(v.y); o.z = f2bf(v.z); o.w = f2bf(v.w);
        ((ushort4*)x16)[idx] = o;
    } else if (bid < CVT_BLOCKS + S1_BLOCKS) {
        int blk = bid - CVT_BLOCKS;
        for (int i = t; i < NBUCK; i += 256) lh[i] = 0;
        __syncthreads();
        int e0 = blk * EPB;
        for (int i = 0; i < 13; i++) {
            int k = t + i * 256;
            if (k < EPB) atomicAdd(&lh[dst[e0 + k] >> BSHIFT], 1);
        }
        __syncthreads();
        for (int i = t; i < NBUCK; i += 256) hist[blk * NBUCK + i] = lh[i];
    } else {
        if (bid == CVT_BLOCKS + S1_BLOCKS) {   // zero BN stats (both layers)
            statsg[t] = 0.f; statsg[t + 256] = 0.f;
        }
        // pack weights into MFMA B-fragment order:
        // Wf[layer][kt(8)][nt(8)][lane(64)][j(8)], lane l holds
        // B[kt*32 + 8*(l>>4) + j][nt*16 + (l&15)].
        int idx = (bid - (CVT_BLOCKS + S1_BLOCKS)) * 256 + t;
        if (idx < 3 * 32768) {
            int layer = idx >> 15;
            int rem = idx & 32767;
            int kt = rem >> 12;
            int nt = (rem >> 9) & 7;
            int lane = (rem >> 3) & 63;
            int j = rem & 7;
            int k = kt * 32 + (lane >> 4) * 8 + j;
            int n = nt * 16 + (lane & 15);
            const float* Wsrc;
            if (layer == 0) Wsrc = (k < 128) ? Ws0 : Wn0;
            else if (layer == 1) Wsrc = (k < 128) ? Ws1 : Wn1;
            else Wsrc = (k < 128) ? Ws2 : Wn2;
            Wf[idx] = f2bf(Wsrc[(k & 127) * D + n]);
        }
    }
}

// ---------------- S2a: per-bucket exclusive prefix over blocks ----------------
// Separate kernels on purpose: round-7's grid-barrier merge (sort_all) ran 97 us
// vs ~35 us for this pipeline — barrier serialization at 1 block/CU.

__global__ void s2a(int* __restrict__ hist, int* __restrict__ bucketTotal) {
    __shared__ int s[S1_BLOCKS];
    int b = blockIdx.x, t = threadIdx.x;
    int v = hist[t * NBUCK + b];
    s[t] = v;
    __syncthreads();
    for (int off = 1; off < S1_BLOCKS; off <<= 1) {
        int x = (t >= off) ? s[t - off] : 0;
        __syncthreads();
        s[t] += x;
        __syncthreads();
    }
    hist[t * NBUCK + b] = s[t] - v;
    if (t == S1_BLOCKS - 1) bucketTotal[b] = s[t];
}

// ---------------- S3: scatter packed records, bucket-grouped ----------------
// Each block redundantly scans the 391 bucket totals in LDS (cheap, parallel —
// removes the s2b dispatch); block 0 publishes bucketStart for s4_build.

__global__ void s3_scatter(const int* __restrict__ src, const int* __restrict__ dst,
                           const int* __restrict__ hist, const int* __restrict__ bucketTotal,
                           int* __restrict__ bucketStart, unsigned int* __restrict__ rec) {
    __shared__ int sc[512];
    __shared__ int base[NBUCK];
    int blk = blockIdx.x, t = threadIdx.x;
    int i1 = t + 256;
    int v0 = (t < NBUCK) ? bucketTotal[t] : 0;
    int v1 = (i1 < NBUCK) ? bucketTotal[i1] : 0;
    sc[t] = v0; sc[i1] = v1;
    __syncthreads();
    for (int off = 1; off < 512; off <<= 1) {
        int x0 = (t >= off) ? sc[t - off] : 0;
        int x1 = (i1 >= off) ? sc[i1 - off] : 0;
        __syncthreads();
        sc[t] += x0; sc[i1] += x1;
        __syncthreads();
    }
    if (t < NBUCK)  base[t]  = (sc[t] - v0)  + hist[blk * NBUCK + t];
    if (i1 < NBUCK) base[i1] = (sc[i1] - v1) + hist[blk * NBUCK + i1];
    if (blk == 0) {
        if (t < NBUCK)  bucketStart[t]  = sc[t] - v0;
        if (i1 < NBUCK) bucketStart[i1] = sc[i1] - v1;
        if (t == 0) bucketStart[NBUCK] = N_EDGES;
    }
    __syncthreads();
    int e0 = blk * EPB;
    for (int i = 0; i < 13; i++) {
        int k = t + i * 256;
        if (k < EPB) {
            int e = e0 + k;
            int d = dst[e];
            int p = atomicAdd(&base[d >> BSHIFT], 1);
            rec[p] = ((unsigned)(d & 127) << 16) | (unsigned)src[e];
        }
    }
}

// ---------------- S4: per-bucket counting sort -> CSR + degrees ----------------

__global__ void s4_build(const unsigned int* __restrict__ rec, const int* __restrict__ bucketStart,
                         unsigned short* __restrict__ csr, int* __restrict__ degi,
                         int* __restrict__ offsets, float* __restrict__ inv_deg) {
    __shared__ int lh[128];
    __shared__ int ls[128];
    __shared__ int lcur[128];
    int b = blockIdx.x, t = threadIdx.x;
    int start = bucketStart[b], end = bucketStart[b + 1];

    if (t < 128) lh[t] = 0;
    __syncthreads();
    for (int e = start + t; e < end; e += 256)
        atomicAdd(&lh[rec[e] >> 16], 1);
    __syncthreads();

    int v = 0;
    if (t < 128) { v = lh[t]; ls[t] = v; }
    __syncthreads();
    for (int off = 1; off < 128; off <<= 1) {
        int x = 0;
        if (t < 128 && t >= off) x = ls[t - off];
        __syncthreads();
        if (t < 128) ls[t] += x;
        __syncthreads();
    }

    int node0 = b << BSHIFT;
    if (t < 128) {
        int excl = ls[t] - v;
        lcur[t] = start + excl;
        int node = node0 + t;
        if (node < N_NODES) {
            degi[node] = v;
            offsets[node] = start + excl;
            inv_deg[node] = 1.0f / (float)max(v, 1);
        }
    }
    __syncthreads();
    for (int e = start + t; e < end; e += 256) {
        unsigned r = rec[e];
        int p = atomicAdd(&lcur[r >> 16], 1);
        csr[p] = (unsigned short)(r & 0xFFFFu);
    }
}

// ---------------- mean aggregation with on-the-fly BN+ReLU ----------------
// h16 holds PRE-BN activations; consumers apply bn+relu (statsIn != nullptr).
// Separate kernel (round-5 lesson: fusing into GEMM block cut TLP, regressed).
// 4-wide software-pipelined edge loop: ~8 outstanding loads/thread to hide
// the ~200-900 cyc gather latency (round-8 counters: VALUBusy 35%, mem-stalled).

#define GATHER(k) (*(const uint4*)(h16 + (size_t)csr[beg + (k)] * D + c * 8))

__global__ void aggregate16(const unsigned short* __restrict__ h16,
                            const unsigned short* __restrict__ csr, const int* __restrict__ offsets,
                            const int* __restrict__ degi, const float* __restrict__ inv_deg,
                            unsigned short* __restrict__ mean16,
                            const float* __restrict__ statsIn,
                            const float* __restrict__ gammaIn, const float* __restrict__ betaIn) {
    int node = blockIdx.x * 16 + (threadIdx.x >> 4);
    if (node >= N_NODES) return;
    int c = threadIdx.x & 15;
    int beg = offsets[node], n = degi[node];
    float a[8];
#pragma unroll
    for (int j = 0; j < 8; j++) a[j] = 0.f;

    if (statsIn) {
        const float invN = 1.0f / (float)N_NODES;
        float sc[8], sh[8];
#pragma unroll
        for (int j = 0; j < 8; j++) {
            int col = c * 8 + j;
            float m = statsIn[col] * invN;
            float var = statsIn[128 + col] * invN - m * m;
            float s = rsqrtf(var + BN_EPS) * gammaIn[col];
            sc[j] = s;
            sh[j] = betaIn[col] - m * s;
        }
        int i = 0;
        if (n >= 4) {
            uint4 v0 = GATHER(0), v1 = GATHER(1), v2 = GATHER(2), v3 = GATHER(3);
            for (i = 4; i + 3 < n; i += 4) {
                uint4 w0 = GATHER(i), w1 = GATHER(i + 1), w2 = GATHER(i + 2), w3 = GATHER(i + 3);
                acc_bn(a, v0, sc, sh); acc_bn(a, v1, sc, sh);
                acc_bn(a, v2, sc, sh); acc_bn(a, v3, sc, sh);
                v0 = w0; v1 = w1; v2 = w2; v3 = w3;
            }
            acc_bn(a, v0, sc, sh); acc_bn(a, v1, sc, sh);
            acc_bn(a, v2, sc, sh); acc_bn(a, v3, sc, sh);
        }
        for (; i < n; i++) { uint4 v = GATHER(i); acc_bn(a, v, sc, sh); }
    } else {
        int i = 0;
        if (n >= 4) {
            uint4 v0 = GATHER(0), v1 = GATHER(1), v2 = GATHER(2), v3 = GATHER(3);
            for (i = 4; i + 3 < n; i += 4) {
                uint4 w0 = GATHER(i), w1 = GATHER(i + 1), w2 = GATHER(i + 2), w3 = GATHER(i + 3);
                acc_plain(a, v0); acc_plain(a, v1); acc_plain(a, v2); acc_plain(a, v3);
                v0 = w0; v1 = w1; v2 = w2; v3 = w3;
            }
            acc_plain(a, v0); acc_plain(a, v1); acc_plain(a, v2); acc_plain(a, v3);
        }
        for (; i < n; i++) { uint4 v = GATHER(i); acc_plain(a, v); }
    }

    float w = inv_deg[node];
    uint4 o;
    o.x = ((unsigned)f2bf(a[1] * w) << 16) | f2bf(a[0] * w);
    o.y = ((unsigned)f2bf(a[3] * w) << 16) | f2bf(a[2] * w);
    o.z = ((unsigned)f2bf(a[5] * w) << 16) | f2bf(a[4] * w);
    o.w = ((unsigned)f2bf(a[7] * w) << 16) | f2bf(a[6] * w);
    *(uint4*)(mean16 + (size_t)node * D + c * 8) = o;
}

// ---------------- MFMA SAGE GEMM + fused BN col-stats ----------------
// out_raw = [bn_relu(h_raw) | mean] @ Wf + b (self half transformed on the fly
// when statsIn != nullptr; mean16 is already post-BN from aggregate16).
// Epilogue: bf16 raw store (layers 0/1) or fp32 (layer 2) + column sum/sumsq.
// C/D layout (m89-verified): col = lane&15, row = (lane>>4)*4 + reg.

__global__ __launch_bounds__(256) void sage_gemm(
    const unsigned short* __restrict__ h16, const unsigned short* __restrict__ mean16,
    const unsigned short* __restrict__ Wf, const float* __restrict__ bias,
    unsigned short* __restrict__ out16, float* __restrict__ outf,
    float* __restrict__ statsOut,
    const float* __restrict__ statsIn,
    const float* __restrict__ gammaIn, const float* __restrict__ betaIn) {
    __shared__ float sstat[256];
    const int t = threadIdx.x;
    const int lane = t & 63;
    const int wave = t >> 6;
    const int m = lane & 15;
    const int quad = lane >> 4;
    const int wrow0 = blockIdx.x * 64 + wave * 16;
    const float invN = 1.0f / (float)N_NODES;

    if (statsOut) {
        sstat[t] = 0.f;
        __syncthreads();
    }

    int arow = wrow0 + m;
    if (arow >= N_NODES) arow = N_NODES - 1;

    f32x4 acc[8];
#pragma unroll
    for (int i = 0; i < 8; i++) acc[i] = (f32x4)(0.f);

#pragma unroll
    for (int kt = 0; kt < 8; kt++) {
        bf16x8 af;
        if (kt < 4) {
            af = *(const bf16x8*)(h16 + (size_t)arow * D + kt * 32 + quad * 8);
            if (statsIn) {   // wave-uniform branch: apply bn+relu to self fragment
                int c0 = kt * 32 + quad * 8;
#pragma unroll
                for (int j = 0; j < 8; j++) {
                    int col = c0 + j;
                    float mm = statsIn[col] * invN;
                    float var = statsIn[128 + col] * invN - mm * mm;
                    float s = rsqrtf(var + BN_EPS) * gammaIn[col];
                    float raw = bf2f((unsigned short)af[j]);
                    float v = fmaxf(raw * s + (betaIn[col] - mm * s), 0.f);
                    af[j] = (short)f2bf(v);
                }
            }
        } else {
            af = *(const bf16x8*)(mean16 + (size_t)arow * D + (kt - 4) * 32 + quad * 8);
        }
#pragma unroll
        for (int nt = 0; nt < 8; nt++) {
            bf16x8 bf = *(const bf16x8*)(Wf + ((kt * 8 + nt) * 64 + lane) * 8);
            acc[nt] = __builtin_amdgcn_mfma_f32_16x16x32_bf16(af, bf, acc[nt], 0, 0, 0);
        }
    }

    const bool do16 = (out16 != nullptr);
#pragma unroll
    for (int nt = 0; nt < 8; nt++) {
        int cidx = nt * 16 + m;
        float bv = bias[cidx];
        float s = 0.f, q = 0.f;
#pragma unroll
        for (int reg = 0; reg < 4; reg++) {
            int r = wrow0 + quad * 4 + reg;
            float v = acc[nt][reg] + bv;
            if (r < N_NODES) {
                if (do16) out16[(size_t)r * D + cidx] = f2bf(v);
                else      outf[(size_t)r * D + cidx] = v;
                s += v; q += v * v;
            }
        }
        if (statsOut) {
            s += __shfl_xor(s, 16); s += __shfl_xor(s, 32);
            q += __shfl_xor(q, 16); q += __shfl_xor(q, 32);
            if (quad == 0) {
                atomicAdd(&sstat[cidx], s);
                atomicAdd(&sstat[128 + cidx], q);
            }
        }
    }
    if (statsOut) {
        __syncthreads();
        atomicAdd(&statsOut[t], sstat[t]);
    }
}

// ---------------- launch ----------------

extern "C" void kernel_launch(void* const* d_in, const int* in_sizes, int n_in,
                              void* d_out, int out_size, void* d_ws, size_t ws_size,
                              hipStream_t stream) {
    const float* x   = (const float*)d_in[0];
    const int* src   = (const int*)d_in[1];
    const int* dst   = (const int*)d_in[2];
    const float* Ws0 = (const float*)d_in[3];
    const float* Wn0 = (const float*)d_in[4];
    const float* b0  = (const float*)d_in[5];
    const float* Ws1 = (const float*)d_in[6];
    const float* Wn1 = (const float*)d_in[7];
    const float* b1  = (const float*)d_in[8];
    const float* Ws2 = (const float*)d_in[9];
    const float* Wn2 = (const float*)d_in[10];
    const float* b2  = (const float*)d_in[11];
    const float* g0  = (const float*)d_in[12];
    const float* be0 = (const float*)d_in[13];
    const float* g1  = (const float*)d_in[14];
    const float* be1 = (const float*)d_in[15];

    char* base = (char*)d_ws;
    size_t NND = (size_t)N_NODES * D;
    unsigned short* X16    = (unsigned short*)base;                 // 12.8 MB: L0 in, then L1 raw out
    unsigned short* H16    = (unsigned short*)(base + NND * 2);     // 12.8 MB: L0 raw out
    unsigned short* mean16 = (unsigned short*)(base + 2 * NND * 2); // 12.8 MB
    char* p = base + 6 * NND;
    unsigned short* Wf = (unsigned short*)p;  p += 3 * 32768 * 2;                  // 192 KB
    int* hist          = (int*)p;             p += (size_t)S1_BLOCKS * NBUCK * 4;  // 400 KB
    int* bucketTotal   = (int*)p;             p += 1568;
    int* bucketStart   = (int*)p;             p += 1600;
    unsigned int* rec  = (unsigned int*)p;    p += (size_t)N_EDGES * 4;            // 3.2 MB
    unsigned short* csr = (unsigned short*)p; p += (size_t)N_EDGES * 2;            // 1.6 MB
    int* degi    = (int*)p;                   p += N_NODES * 4;
    int* offsets = (int*)p;                   p += N_NODES * 4;
    float* inv_deg = (float*)p;               p += N_NODES * 4;
    float* stats   = (float*)p;               p += 2048;  // [2][sum128|sumsq128]
    float* stats0 = stats, *stats1 = stats + 256;

    // prep: feature convert + edge histogram + weight pack + zero stats
    fused_prep<<<CVT_BLOCKS + S1_BLOCKS + PACK_BLOCKS, 256, 0, stream>>>(
        x, X16, dst, hist, Ws0, Wn0, Ws1, Wn1, Ws2, Wn2, Wf, stats);
    // CSR build: 3 kernels (s2b folded into s3 as redundant per-block scan)
    s2a<<<NBUCK, 256, 0, stream>>>(hist, bucketTotal);
    s3_scatter<<<S1_BLOCKS, 256, 0, stream>>>(src, dst, hist, bucketTotal, bucketStart, rec);
    s4_build<<<NBUCK, 256, 0, stream>>>(rec, bucketStart, csr, degi, offsets, inv_deg);

    const int AGG_B = (N_NODES + 15) / 16;   // 3125
    const int GEMM_B = (N_NODES + 63) / 64;  // 782

    // Layer 0: X16 (no BN) -> H16 raw + stats0
    aggregate16<<<AGG_B, 256, 0, stream>>>(X16, csr, offsets, degi, inv_deg, mean16,
                                           nullptr, nullptr, nullptr);
    sage_gemm<<<GEMM_B, 256, 0, stream>>>(X16, mean16, Wf, b0, H16, nullptr,
                                          stats0, nullptr, nullptr, nullptr);

    // Layer 1: consumers apply bn0+relu to H16 raw; -> X16 raw + stats1
    aggregate16<<<AGG_B, 256, 0, stream>>>(H16, csr, offsets, degi, inv_deg, mean16,
                                           stats0, g0, be0);
    sage_gemm<<<GEMM_B, 256, 0, stream>>>(H16, mean16, Wf + 32768, b1, X16, nullptr,
                                          stats1, stats0, g0, be0);

    // Layer 2: consumers apply bn1+relu to X16 raw; -> d_out fp32
    aggregate16<<<AGG_B, 256, 0, stream>>>(X16, csr, offsets, degi, inv_deg, mean16,
                                           stats1, g1, be1);
    sage_gemm<<<GEMM_B, 256, 0, stream>>>(X16, mean16, Wf + 65536, b2, nullptr,
                                          (float*)d_out, nullptr, stats1, g1, be1);
}

// Round 10
// 317.533 us; speedup vs baseline: 1.3049x; 1.0433x over previous
//
#include <hip/hip_runtime.h>

#define N_NODES 50000
#define N_EDGES 800000
#define D 128
#define BN_EPS 1e-5f

#define NBUCK 391        // ceil(N_NODES / 128)
#define BSHIFT 7         // 128 nodes per bucket
#define S1_BLOCKS 256
#define EPB 3125         // edges per histogram/scatter block (256*3125 == 800000)
#define CVT_BLOCKS 6250  // N_NODES*D/4 / 256
#define PACK_BLOCKS 384  // 3*32768 / 256
#define NREP 8           // stats replica count (atomic-contention spread)

typedef __attribute__((ext_vector_type(8))) short bf16x8;
typedef __attribute__((ext_vector_type(4))) float f32x4;

// fp32 -> bf16 (RNE)
__device__ inline unsigned short f2bf(float f) {
    unsigned int u = __float_as_uint(f);
    u = (u + 0x7FFF + ((u >> 16) & 1)) >> 16;
    return (unsigned short)u;
}

__device__ inline float bf2f(unsigned short b) {
    return __uint_as_float(((unsigned)b) << 16);
}

__device__ __forceinline__ void acc_plain(float* a, uint4 v) {
    unsigned w[4] = {v.x, v.y, v.z, v.w};
#pragma unroll
    for (int p = 0; p < 4; p++) {
        a[2 * p]     += __uint_as_float(w[p] << 16);
        a[2 * p + 1] += __uint_as_float(w[p] & 0xffff0000u);
    }
}

__device__ __forceinline__ void acc_bn(float* a, uint4 v, const float* sc, const float* sh) {
    unsigned w[4] = {v.x, v.y, v.z, v.w};
#pragma unroll
    for (int p = 0; p < 4; p++) {
        float lo = __uint_as_float(w[p] << 16);
        float hi = __uint_as_float(w[p] & 0xffff0000u);
        a[2 * p]     += fmaxf(lo * sc[2 * p]     + sh[2 * p],     0.f);
        a[2 * p + 1] += fmaxf(hi * sc[2 * p + 1] + sh[2 * p + 1], 0.f);
    }
}

// ---------------- fused prep: convert_x | edge histogram | pack_w (+zero) ----------

__global__ void fused_prep(const float* __restrict__ x, unsigned short* __restrict__ x16,
                           const int* __restrict__ dst, int* __restrict__ hist,
                           const float* __restrict__ Ws0, const float* __restrict__ Wn0,
                           const float* __restrict__ Ws1, const float* __restrict__ Wn1,
                           const float* __restrict__ Ws2, const float* __restrict__ Wn2,
                           unsigned short* __restrict__ Wf, float* __restrict__ statsg) {
    __shared__ int lh[NBUCK];
    const int bid = blockIdx.x, t = threadIdx.x;

    if (bid < CVT_BLOCKS) {
        int idx = bid * 256 + t;
        float4 v = ((const float4*)x)[idx];
        ushort4 o;
        o.x = f2bf(v.x); o.y = f2bf(v.y); o.z = f2bf(v.z); o.w = f2bf(v.w);
        ((ushort4*)x16)[idx] = o;
    } else if (bid < CVT_BLOCKS + S1_BLOCKS) {
        int blk = bid - CVT_BLOCKS;
        for (int i = t; i < NBUCK; i += 256) lh[i] = 0;
        __syncthreads();
        int e0 = blk * EPB;
        for (int i = 0; i < 13; i++) {
            int k = t + i * 256;
            if (k < EPB) atomicAdd(&lh[dst[e0 + k] >> BSHIFT], 1);
        }
        __syncthreads();
        for (int i = t; i < NBUCK; i += 256) hist[blk * NBUCK + i] = lh[i];
    } else {
        if (bid == CVT_BLOCKS + S1_BLOCKS) {   // zero BN stats: 2 layers x NREP x 256
            for (int i = t; i < 2 * NREP * 256; i += 256) statsg[i] = 0.f;
        }
        // pack weights into MFMA B-fragment order:
        // Wf[layer][kt(8)][nt(8)][lane(64)][j(8)], lane l holds
        // B[kt*32 + 8*(l>>4) + j][nt*16 + (l&15)].
        int idx = (bid - (CVT_BLOCKS + S1_BLOCKS)) * 256 + t;
        if (idx < 3 * 32768) {
            int layer = idx >> 15;
            int rem = idx & 32767;
            int kt = rem >> 12;
            int nt = (rem >> 9) & 7;
            int lane = (rem >> 3) & 63;
            int j = rem & 7;
            int k = kt * 32 + (lane >> 4) * 8 + j;
            int n = nt * 16 + (lane & 15);
            const float* Wsrc;
            if (layer == 0) Wsrc = (k < 128) ? Ws0 : Wn0;
            else if (layer == 1) Wsrc = (k < 128) ? Ws1 : Wn1;
            else Wsrc = (k < 128) ? Ws2 : Wn2;
            Wf[idx] = f2bf(Wsrc[(k & 127) * D + n]);
        }
    }
}

// ---------------- S2a: per-bucket exclusive prefix over blocks ----------------
// Separate kernels on purpose: round-7's grid-barrier merge (sort_all) ran 97 us
// vs ~35 us for this pipeline — barrier serialization at 1 block/CU.

__global__ void s2a(int* __restrict__ hist, int* __restrict__ bucketTotal) {
    __shared__ int s[S1_BLOCKS];
    int b = blockIdx.x, t = threadIdx.x;
    int v = hist[t * NBUCK + b];
    s[t] = v;
    __syncthreads();
    for (int off = 1; off < S1_BLOCKS; off <<= 1) {
        int x = (t >= off) ? s[t - off] : 0;
        __syncthreads();
        s[t] += x;
        __syncthreads();
    }
    hist[t * NBUCK + b] = s[t] - v;
    if (t == S1_BLOCKS - 1) bucketTotal[b] = s[t];
}

// ---------------- S3: scatter packed records, bucket-grouped ----------------
// Each block redundantly scans the 391 bucket totals in LDS (cheap, parallel —
// removes the s2b dispatch); block 0 publishes bucketStart for s4_build.

__global__ void s3_scatter(const int* __restrict__ src, const int* __restrict__ dst,
                           const int* __restrict__ hist, const int* __restrict__ bucketTotal,
                           int* __restrict__ bucketStart, unsigned int* __restrict__ rec) {
    __shared__ int sc[512];
    __shared__ int base[NBUCK];
    int blk = blockIdx.x, t = threadIdx.x;
    int i1 = t + 256;
    int v0 = (t < NBUCK) ? bucketTotal[t] : 0;
    int v1 = (i1 < NBUCK) ? bucketTotal[i1] : 0;
    sc[t] = v0; sc[i1] = v1;
    __syncthreads();
    for (int off = 1; off < 512; off <<= 1) {
        int x0 = (t >= off) ? sc[t - off] : 0;
        int x1 = (i1 >= off) ? sc[i1 - off] : 0;
        __syncthreads();
        sc[t] += x0; sc[i1] += x1;
        __syncthreads();
    }
    if (t < NBUCK)  base[t]  = (sc[t] - v0)  + hist[blk * NBUCK + t];
    if (i1 < NBUCK) base[i1] = (sc[i1] - v1) + hist[blk * NBUCK + i1];
    if (blk == 0) {
        if (t < NBUCK)  bucketStart[t]  = sc[t] - v0;
        if (i1 < NBUCK) bucketStart[i1] = sc[i1] - v1;
        if (t == 0) bucketStart[NBUCK] = N_EDGES;
    }
    __syncthreads();
    int e0 = blk * EPB;
    for (int i = 0; i < 13; i++) {
        int k = t + i * 256;
        if (k < EPB) {
            int e = e0 + k;
            int d = dst[e];
            int p = atomicAdd(&base[d >> BSHIFT], 1);
            rec[p] = ((unsigned)(d & 127) << 16) | (unsigned)src[e];
        }
    }
}

// ---------------- S4: per-bucket counting sort -> CSR + degrees ----------------

__global__ void s4_build(const unsigned int* __restrict__ rec, const int* __restrict__ bucketStart,
                         unsigned short* __restrict__ csr, int* __restrict__ degi,
                         int* __restrict__ offsets, float* __restrict__ inv_deg) {
    __shared__ int lh[128];
    __shared__ int ls[128];
    __shared__ int lcur[128];
    int b = blockIdx.x, t = threadIdx.x;
    int start = bucketStart[b], end = bucketStart[b + 1];

    if (t < 128) lh[t] = 0;
    __syncthreads();
    for (int e = start + t; e < end; e += 256)
        atomicAdd(&lh[rec[e] >> 16], 1);
    __syncthreads();

    int v = 0;
    if (t < 128) { v = lh[t]; ls[t] = v; }
    __syncthreads();
    for (int off = 1; off < 128; off <<= 1) {
        int x = 0;
        if (t < 128 && t >= off) x = ls[t - off];
        __syncthreads();
        if (t < 128) ls[t] += x;
        __syncthreads();
    }

    int node0 = b << BSHIFT;
    if (t < 128) {
        int excl = ls[t] - v;
        lcur[t] = start + excl;
        int node = node0 + t;
        if (node < N_NODES) {
            degi[node] = v;
            offsets[node] = start + excl;
            inv_deg[node] = 1.0f / (float)max(v, 1);
        }
    }
    __syncthreads();
    for (int e = start + t; e < end; e += 256) {
        unsigned r = rec[e];
        int p = atomicAdd(&lcur[r >> 16], 1);
        csr[p] = (unsigned short)(r & 0xFFFFu);
    }
}

// ---------------- mean aggregation with on-the-fly BN+ReLU ----------------
// h16 holds PRE-BN activations; statsIn (NREP-replicated) => apply bn+relu.
// Block 0 also publishes the folded sc/sh table for the following sage_gemm.
// Separate kernel (round-5 lesson); 4-wide software-pipelined edge loop (round-9).

#define GATHER(k) (*(const uint4*)(h16 + (size_t)csr[beg + (k)] * D + c * 8))

__global__ void aggregate16(const unsigned short* __restrict__ h16,
                            const unsigned short* __restrict__ csr, const int* __restrict__ offsets,
                            const int* __restrict__ degi, const float* __restrict__ inv_deg,
                            unsigned short* __restrict__ mean16,
                            const float* __restrict__ statsIn,
                            const float* __restrict__ gammaIn, const float* __restrict__ betaIn,
                            float* __restrict__ scshG) {
    int t = threadIdx.x;
    // block 0: publish folded BN table (sc[128] | sh[128]) for sage_gemm
    if (statsIn && blockIdx.x == 0 && t < 128) {
        const float invN = 1.0f / (float)N_NODES;
        float s = 0.f, q = 0.f;
#pragma unroll
        for (int r = 0; r < NREP; r++) {
            s += statsIn[r * 256 + t];
            q += statsIn[r * 256 + 128 + t];
        }
        float m = s * invN;
        float var = q * invN - m * m;
        float scv = rsqrtf(var + BN_EPS) * gammaIn[t];
        scshG[t] = scv;
        scshG[128 + t] = betaIn[t] - m * scv;
    }

    int node = blockIdx.x * 16 + (t >> 4);
    if (node >= N_NODES) return;
    int c = t & 15;
    int beg = offsets[node], n = degi[node];
    float a[8];
#pragma unroll
    for (int j = 0; j < 8; j++) a[j] = 0.f;

    if (statsIn) {
        const float invN = 1.0f / (float)N_NODES;
        float sc[8], sh[8];
#pragma unroll
        for (int j = 0; j < 8; j++) {
            int col = c * 8 + j;
            float s = 0.f, q = 0.f;
#pragma unroll
            for (int r = 0; r < NREP; r++) {
                s += statsIn[r * 256 + col];
                q += statsIn[r * 256 + 128 + col];
            }
            float m = s * invN;
            float var = q * invN - m * m;
            float scv = rsqrtf(var + BN_EPS) * gammaIn[col];
            sc[j] = scv;
            sh[j] = betaIn[col] - m * scv;
        }
        int i = 0;
        if (n >= 4) {
            uint4 v0 = GATHER(0), v1 = GATHER(1), v2 = GATHER(2), v3 = GATHER(3);
            for (i = 4; i + 3 < n; i += 4) {
                uint4 w0 = GATHER(i), w1 = GATHER(i + 1), w2 = GATHER(i + 2), w3 = GATHER(i + 3);
                acc_bn(a, v0, sc, sh); acc_bn(a, v1, sc, sh);
                acc_bn(a, v2, sc, sh); acc_bn(a, v3, sc, sh);
                v0 = w0; v1 = w1; v2 = w2; v3 = w3;
            }
            acc_bn(a, v0, sc, sh); acc_bn(a, v1, sc, sh);
            acc_bn(a, v2, sc, sh); acc_bn(a, v3, sc, sh);
        }
        for (; i < n; i++) { uint4 v = GATHER(i); acc_bn(a, v, sc, sh); }
    } else {
        int i = 0;
        if (n >= 4) {
            uint4 v0 = GATHER(0), v1 = GATHER(1), v2 = GATHER(2), v3 = GATHER(3);
            for (i = 4; i + 3 < n; i += 4) {
                uint4 w0 = GATHER(i), w1 = GATHER(i + 1), w2 = GATHER(i + 2), w3 = GATHER(i + 3);
                acc_plain(a, v0); acc_plain(a, v1); acc_plain(a, v2); acc_plain(a, v3);
                v0 = w0; v1 = w1; v2 = w2; v3 = w3;
            }
            acc_plain(a, v0); acc_plain(a, v1); acc_plain(a, v2); acc_plain(a, v3);
        }
        for (; i < n; i++) { uint4 v = GATHER(i); acc_plain(a, v); }
    }

    float w = inv_deg[node];
    uint4 o;
    o.x = ((unsigned)f2bf(a[1] * w) << 16) | f2bf(a[0] * w);
    o.y = ((unsigned)f2bf(a[3] * w) << 16) | f2bf(a[2] * w);
    o.z = ((unsigned)f2bf(a[5] * w) << 16) | f2bf(a[4] * w);
    o.w = ((unsigned)f2bf(a[7] * w) << 16) | f2bf(a[6] * w);
    *(uint4*)(mean16 + (size_t)node * D + c * 8) = o;
}

// ---------------- MFMA SAGE GEMM + fused BN col-stats ----------------
// Round-10 restructure (round-9 counters: MfmaUtil 2.4%, 56 VGPR => B-frag
// loads serialized at L2 latency; stats atomics 782-way contended):
//  - Wf staged in LDS 32KB at a time; B-frags via ds_read_b128.
//  - All 8 A-frags register-prefetched up front; self half BN'd via scshG table.
//  - Stats scattered across NREP replica slots (blockIdx&7).
// C/D layout (m89-verified): col = lane&15, row = (lane>>4)*4 + reg.

__global__ __launch_bounds__(256, 4) void sage_gemm(
    const unsigned short* __restrict__ h16, const unsigned short* __restrict__ mean16,
    const unsigned short* __restrict__ Wf, const float* __restrict__ bias,
    unsigned short* __restrict__ out16, float* __restrict__ outf,
    float* __restrict__ statsOut, const float* __restrict__ scshG) {
    __shared__ unsigned short sWf[16384];   // 32 KB: one K-half (4 kt x 8 nt x 64 x 8)
    __shared__ float sstat[256];
    const int t = threadIdx.x;
    const int lane = t & 63;
    const int m = lane & 15;
    const int quad = lane >> 4;
    const int wrow0 = blockIdx.x * 64 + (t >> 6) * 16;

    int arow = wrow0 + m;
    if (arow >= N_NODES) arow = N_NODES - 1;

    // prefetch all 8 A-fragments (4 self + 4 mean) into registers
    bf16x8 afr[8];
#pragma unroll
    for (int kt = 0; kt < 4; kt++)
        afr[kt] = *(const bf16x8*)(h16 + (size_t)arow * D + kt * 32 + quad * 8);
#pragma unroll
    for (int kt = 0; kt < 4; kt++)
        afr[4 + kt] = *(const bf16x8*)(mean16 + (size_t)arow * D + kt * 32 + quad * 8);

    // stage first weight half (kt 0-3)
    const uint4* W4 = (const uint4*)Wf;
    uint4* S4 = (uint4*)sWf;
#pragma unroll
    for (int i = 0; i < 8; i++) S4[i * 256 + t] = W4[i * 256 + t];
    if (statsOut) sstat[t] = 0.f;
    __syncthreads();

    // BN+ReLU on self fragments (table published by aggregate16)
    if (scshG) {
#pragma unroll
        for (int kt = 0; kt < 4; kt++) {
            int c0 = kt * 32 + quad * 8;
            float4 sca = *(const float4*)(scshG + c0);
            float4 scb = *(const float4*)(scshG + c0 + 4);
            float4 sha = *(const float4*)(scshG + 128 + c0);
            float4 shb = *(const float4*)(scshG + 128 + c0 + 4);
            float scv[8] = {sca.x, sca.y, sca.z, sca.w, scb.x, scb.y, scb.z, scb.w};
            float shv[8] = {sha.x, sha.y, sha.z, sha.w, shb.x, shb.y, shb.z, shb.w};
#pragma unroll
            for (int j = 0; j < 8; j++) {
                float v = fmaxf(bf2f((unsigned short)afr[kt][j]) * scv[j] + shv[j], 0.f);
                afr[kt][j] = (short)f2bf(v);
            }
        }
    }

    f32x4 acc[8];
#pragma unroll
    for (int i = 0; i < 8; i++) acc[i] = (f32x4)(0.f);

#pragma unroll
    for (int kt = 0; kt < 4; kt++) {
#pragma unroll
        for (int nt = 0; nt < 8; nt++) {
            bf16x8 bf = *(const bf16x8*)(sWf + ((kt * 8 + nt) * 64 + lane) * 8);
            acc[nt] = __builtin_amdgcn_mfma_f32_16x16x32_bf16(afr[kt], bf, acc[nt], 0, 0, 0);
        }
    }

    __syncthreads();   // all waves done with half 1 before overwrite
#pragma unroll
    for (int i = 0; i < 8; i++) S4[i * 256 + t] = W4[2048 + i * 256 + t];
    __syncthreads();

#pragma unroll
    for (int kt = 4; kt < 8; kt++) {
#pragma unroll
        for (int nt = 0; nt < 8; nt++) {
            bf16x8 bf = *(const bf16x8*)(sWf + (((kt - 4) * 8 + nt) * 64 + lane) * 8);
            acc[nt] = __builtin_amdgcn_mfma_f32_16x16x32_bf16(afr[kt], bf, acc[nt], 0, 0, 0);
        }
    }

    const bool do16 = (out16 != nullptr);
#pragma unroll
    for (int nt = 0; nt < 8; nt++) {
        int cidx = nt * 16 + m;
        float bv = bias[cidx];
        float s = 0.f, q = 0.f;
#pragma unroll
        for (int reg = 0; reg < 4; reg++) {
            int r = wrow0 + quad * 4 + reg;
            float v = acc[nt][reg] + bv;
            if (r < N_NODES) {
                if (do16) out16[(size_t)r * D + cidx] = f2bf(v);
                else      outf[(size_t)r * D + cidx] = v;
                s += v; q += v * v;
            }
        }
        if (statsOut) {
            s += __shfl_xor(s, 16); s += __shfl_xor(s, 32);
            q += __shfl_xor(q, 16); q += __shfl_xor(q, 32);
            if (quad == 0) {
                atomicAdd(&sstat[cidx], s);
                atomicAdd(&sstat[128 + cidx], q);
            }
        }
    }
    if (statsOut) {
        __syncthreads();
        atomicAdd(&statsOut[(blockIdx.x & (NREP - 1)) * 256 + t], sstat[t]);
    }
}

// ---------------- launch ----------------

extern "C" void kernel_launch(void* const* d_in, const int* in_sizes, int n_in,
                              void* d_out, int out_size, void* d_ws, size_t ws_size,
                              hipStream_t stream) {
    const float* x   = (const float*)d_in[0];
    const int* src   = (const int*)d_in[1];
    const int* dst   = (const int*)d_in[2];
    const float* Ws0 = (const float*)d_in[3];
    const float* Wn0 = (const float*)d_in[4];
    const float* b0  = (const float*)d_in[5];
    const float* Ws1 = (const float*)d_in[6];
    const float* Wn1 = (const float*)d_in[7];
    const float* b1  = (const float*)d_in[8];
    const float* Ws2 = (const float*)d_in[9];
    const float* Wn2 = (const float*)d_in[10];
    const float* b2  = (const float*)d_in[11];
    const float* g0  = (const float*)d_in[12];
    const float* be0 = (const float*)d_in[13];
    const float* g1  = (const float*)d_in[14];
    const float* be1 = (const float*)d_in[15];

    char* base = (char*)d_ws;
    size_t NND = (size_t)N_NODES * D;
    unsigned short* X16    = (unsigned short*)base;                 // 12.8 MB
    unsigned short* H16    = (unsigned short*)(base + NND * 2);     // 12.8 MB
    unsigned short* mean16 = (unsigned short*)(base + 2 * NND * 2); // 12.8 MB
    char* p = base + 6 * NND;
    unsigned short* Wf = (unsigned short*)p;  p += 3 * 32768 * 2;                  // 192 KB
    int* hist          = (int*)p;             p += (size_t)S1_BLOCKS * NBUCK * 4;  // 400 KB
    int* bucketTotal   = (int*)p;             p += 1568;
    int* bucketStart   = (int*)p;             p += 1600;
    unsigned int* rec  = (unsigned int*)p;    p += (size_t)N_EDGES * 4;            // 3.2 MB
    unsigned short* csr = (unsigned short*)p; p += (size_t)N_EDGES * 2;            // 1.6 MB
    int* degi    = (int*)p;                   p += N_NODES * 4;
    int* offsets = (int*)p;                   p += N_NODES * 4;
    float* inv_deg = (float*)p;               p += N_NODES * 4;
    float* stats   = (float*)p;               p += 2 * NREP * 256 * 4;  // replicated
    float* scsh    = (float*)p;               p += 1024;               // sc[128]|sh[128]
    float* stats0 = stats, *stats1 = stats + NREP * 256;

    // prep: feature convert + edge histogram + weight pack + zero stats
    fused_prep<<<CVT_BLOCKS + S1_BLOCKS + PACK_BLOCKS, 256, 0, stream>>>(
        x, X16, dst, hist, Ws0, Wn0, Ws1, Wn1, Ws2, Wn2, Wf, stats);
    // CSR build: 3 kernels (s2b folded into s3 as redundant per-block scan)
    s2a<<<NBUCK, 256, 0, stream>>>(hist, bucketTotal);
    s3_scatter<<<S1_BLOCKS, 256, 0, stream>>>(src, dst, hist, bucketTotal, bucketStart, rec);
    s4_build<<<NBUCK, 256, 0, stream>>>(rec, bucketStart, csr, degi, offsets, inv_deg);

    const int AGG_B = (N_NODES + 15) / 16;   // 3125
    const int GEMM_B = (N_NODES + 63) / 64;  // 782

    // Layer 0: X16 (no BN) -> H16 raw + stats0
    aggregate16<<<AGG_B, 256, 0, stream>>>(X16, csr, offsets, degi, inv_deg, mean16,
                                           nullptr, nullptr, nullptr, nullptr);
    sage_gemm<<<GEMM_B, 256, 0, stream>>>(X16, mean16, Wf, b0, H16, nullptr,
                                          stats0, nullptr);

    // Layer 1: consumers apply bn0+relu to H16 raw; -> X16 raw + stats1
    aggregate16<<<AGG_B, 256, 0, stream>>>(H16, csr, offsets, degi, inv_deg, mean16,
                                           stats0, g0, be0, scsh);
    sage_gemm<<<GEMM_B, 256, 0, stream>>>(H16, mean16, Wf + 32768, b1, X16, nullptr,
                                          stats1, scsh);

    // Layer 2: consumers apply bn1+relu to X16 raw; -> d_out fp32
    aggregate16<<<AGG_B, 256, 0, stream>>>(X16, csr, offsets, degi, inv_deg, mean16,
                                           stats1, g1, be1, scsh);
    sage_gemm<<<GEMM_B, 256, 0, stream>>>(X16, mean16, Wf + 65536, b2, nullptr,
                                          (float*)d_out, nullptr, scsh);
}